// Round 5
// baseline (266.135 us; speedup 1.0000x reference)
//
#include <hip/hip_runtime.h>
#include <hip/hip_bf16.h>
#include <math.h>

#define BB 8
#define CC 64
#define NN 500
#define TT 12
#define HH 4
#define FF 64
#define CT (CC*TT)      // 768
#define HF (HH*FF)      // 256
#define NBT (HH*TT)     // 48
#define NBHT (BB*NBT)   // 384
#define NROWS (BB*HH*TT*NN)  // 192000
#define NNODE (BB*NN)   // 4000
#define BSR 200         // k45 LDS row stride (ushorts)
#define KST 68          // k2 LDS B row stride (ushorts)
#define WTS 520         // k2 WT-lds t-row stride (ushorts)
#define WTILE 32768     // packed WhT tile size per bht (ushorts) = 64KB

typedef unsigned short ushort_t;
typedef unsigned int uint_t;
typedef __attribute__((ext_vector_type(8))) short short8;
typedef __attribute__((ext_vector_type(4))) float floatx4;
typedef __attribute__((ext_vector_type(2))) float float2v;

static __device__ __forceinline__ ushort_t f2bf(float v) {
    __hip_bfloat16 h = __float2bfloat16(v);
    ushort_t u;
    __builtin_memcpy(&u, &h, 2);
    return u;
}

static __device__ __forceinline__ float bf2f(ushort_t u) {
    return __uint_as_float(((uint_t)u) << 16);
}

// pack two f32 -> packed bf16 (lo = a, hi = b), RNE (hw v_cvt_pk on gfx950)
static __device__ __forceinline__ uint_t pkbf(float a, float b) {
    __hip_bfloat162 h = __float22bfloat162_rn(make_float2(a, b));
    uint_t u;
    __builtin_memcpy(&u, &h, 4);
    return u;
}

// Packed WhT layout, per bht tile of WTILE ushorts:
//   element (f = ft*16 + r, m = ki*32 + q*8 + j)
//   -> offset (ki*4 + ft)*512 + q*128 + r*8 + j
// so k3's B-fragment load for (ki, ft) is lane*8 contiguous (1KB/instr).

// ---------------------------------------------------------------------------
// K016: merged setup + x-transpose(->bf16) + packed-WhT tail zero.
// ---------------------------------------------------------------------------
__global__ __launch_bounds__(256) void k016_setup(const float* __restrict__ adj,
                                                  const float* __restrict__ W,
                                                  const float* __restrict__ a1,
                                                  const float* __restrict__ a2,
                                                  const float* __restrict__ Wm,
                                                  const float* __restrict__ Wg,
                                                  const float* __restrict__ x,
                                                  uint_t* __restrict__ maskbits,
                                                  float* __restrict__ p1,
                                                  float* __restrict__ p2,
                                                  ushort_t* __restrict__ WmB,
                                                  ushort_t* __restrict__ WgB,
                                                  ushort_t* __restrict__ WtB,
                                                  ushort_t* __restrict__ xB,
                                                  ushort_t* __restrict__ WhT) {
    __shared__ float tile[16*776];   // used by the x-transpose path only
    int blk = blockIdx.x;
    if (blk < 32) {
        int idx = blk * 256 + threadIdx.x;   // < 512*16
        int n = idx >> 4, j = idx & 15;      // dword j covers m = j*32..+31
        uint_t v = 0;
        if (n < NN) {
            int m0 = j * 32;
            for (int i = 0; i < 32; ++i) {
                int m = m0 + i;
                bool p = (m < NN) && (adj[n*NN + m] > 0.f || m == n);
                v |= (p ? 1u : 0u) << i;
            }
        }
        maskbits[idx] = v;
        return;
    }
    if (blk < 209) {
        int idx = (blk - 32) * 256 + threadIdx.x;
        if (idx < HH*CC) {
            int h = idx / CC, c = idx % CC;
            float s1 = 0.f, s2 = 0.f;
            for (int f = 0; f < FF; ++f) {
                float w = W[(h*CC + c)*FF + f];
                s1 += w * a1[h*FF + f];
                s2 += w * a2[h*FF + f];
            }
            p1[idx] = s1; p2[idx] = s2;
        }
        int j = idx - HH*CC;
        if (j >= 0 && j < CC*3*CC) {          // WmB = bf16(Wm), [o][192]
            WmB[j] = f2bf(Wm[j]);
        }
        int j2 = idx - (HH*CC + CC*3*CC);
        if (j2 >= 0 && j2 < FF*HF) {
            WgB[j2] = f2bf(Wg[j2]);
        }
        int j3 = idx - (HH*CC + CC*3*CC + FF*HF);
        if (j3 >= 0 && j3 < HH*CC*FF) {       // WtB[h][f][c] = W[h][c][f]
            int h = j3 >> 12, rem = j3 & 4095;
            int f = rem >> 6, c = rem & 63;
            WtB[j3] = f2bf(W[h*4096 + c*64 + f]);
        }
        return;
    }
    if (blk >= 465) {                         // packed WhT tail zero: m in [500,512)
        int task = (blk - 465) * 256 + threadIdx.x;   // < 24576 = 384*64
        int tilei = task >> 6;       // 0..383 (bht)
        int ft    = (task >> 4) & 3;
        int r     = task & 15;
        ushort_t* base = WhT + (size_t)tilei*WTILE + (size_t)(15*4 + ft)*512;
        // m = 500..503: ki=15, q=2, j=4..7
        *(uint_t*)(base + 2*128 + r*8 + 4) = 0;
        *(uint_t*)(base + 2*128 + r*8 + 6) = 0;
        // m = 504..511: ki=15, q=3, j=0..7
        *(short8*)(base + 3*128 + r*8) = (short8){0,0,0,0,0,0,0,0};
        return;
    }
    // x-transpose: blocks 209..464 -> xblk 0..255; out bf16 [t][64c]
    int xblk = blk - 209;
    int b  = xblk >> 5;
    int n0 = (xblk & 31) * 16;
    for (int idx = threadIdx.x; idx < CC*16*TT; idx += 256) {
        int c   = idx / (16*TT);
        int rem = idx % (16*TT);
        int nl  = rem / TT;
        int t   = rem % TT;
        int n   = n0 + nl;
        if (n < NN)
            tile[nl*776 + c*TT + t] = x[((b*CC + c)*NN + n)*TT + t];
    }
    __syncthreads();
    for (int idx = threadIdx.x; idx < 16*384; idx += 256) {
        int nl = idx / 384, j = idx % 384;    // j = t*32 + c2
        int t = j >> 5, c2 = j & 31;
        int n = n0 + nl;
        if (n < NN) {
            float v0 = tile[nl*776 + (2*c2)*TT + t];
            float v1 = tile[nl*776 + (2*c2 + 1)*TT + t];
            *(uint_t*)&xB[(size_t)(b*NN + n)*CT + t*64 + 2*c2] = pkbf(v0, v1);
        }
    }
}

// ---------------------------------------------------------------------------
// K2: Wh via MFMA, writing packed WhT directly (layer 1; input xB).
// ---------------------------------------------------------------------------
__global__ __launch_bounds__(256) void k2_wh_e(const ushort_t* __restrict__ hinB,
                                               const ushort_t* __restrict__ WtB,
                                               const float* __restrict__ p1,
                                               const float* __restrict__ p2,
                                               ushort_t* __restrict__ WhT,
                                               float* __restrict__ e1,
                                               float* __restrict__ e2) {
    __shared__ ushort_t WTu[4*TT*WTS];    // 49920 B (per-wave transpose bufs)
    __shared__ ushort_t Bs[8][TT*KST];    // 13056 B
    int tid  = threadIdx.x;
    int wid  = tid >> 6;                  // wave = head h
    int lane = tid & 63;
    int quad = lane >> 4;
    int r    = lane & 15;
    int b    = blockIdx.x / 63;
    int nl0  = (blockIdx.x % 63) * 8;     // local m base (0..496)

    for (int i = tid; i < 8*TT*8; i += 256) {   // 768 short8 tasks
        int u = i / 96, rem = i % 96;
        int t = rem >> 3, c8 = rem & 7;
        int node = b*NN + nl0 + u;
        if (node > NNODE-1) node = NNODE-1;
        short8 v = *(const short8*)(hinB + (size_t)node*CT + t*64 + c8*8);
        *(short8*)&Bs[u][t*KST + c8*8] = v;
    }
    __syncthreads();

    {   // e1/e2 (fp32 accum from bf16 h)
        int t2 = lane & 15, h2 = lane >> 4;
        if (t2 < TT) {
            for (int pass = 0; pass < 2; ++pass) {
                int u  = wid + pass*4;
                int nl = nl0 + u;
                if (nl < NN) {
                    const ushort_t* Bu = Bs[u];
                    float s1 = 0.f, s2 = 0.f;
                    for (int c = 0; c < CC; ++c) {
                        float v = bf2f(Bu[t2*KST + c]);
                        s1 += v * p1[h2*CC + c];
                        s2 += v * p2[h2*CC + c];
                    }
                    int idx = ((b*HH + h2)*TT + t2)*NN + nl;
                    e1[idx] = s1;
                    e2[idx] = s2;
                }
            }
        }
    }

    ushort_t* WTl = WTu + wid*(TT*WTS);   // [12][520], wave-private

    short8 Afr[4][2];
    #pragma unroll
    for (int mt = 0; mt < 4; ++mt)
        #pragma unroll
        for (int kc = 0; kc < 2; ++kc)
            Afr[mt][kc] = *(const short8*)(WtB + wid*4096 +
                                           (mt*16 + r)*64 + kc*32 + quad*8);

    int rcl = r < TT ? r : TT-1;

    for (int u = 0; u < 8; ++u) {
        bool valid = (nl0 + u) < NN;
        floatx4 C[4];
        #pragma unroll
        for (int mt = 0; mt < 4; ++mt) C[mt] = (floatx4){0.f,0.f,0.f,0.f};
        #pragma unroll
        for (int kc = 0; kc < 2; ++kc) {
            short8 bfr = *(const short8*)&Bs[u][rcl*KST + kc*32 + quad*8];
            #pragma unroll
            for (int mt = 0; mt < 4; ++mt)
                C[mt] = __builtin_amdgcn_mfma_f32_16x16x32_bf16(Afr[mt][kc], bfr, C[mt], 0, 0, 0);
        }
        if (r < TT) {
            #pragma unroll
            for (int mt = 0; mt < 4; ++mt) {
                #pragma unroll
                for (int reg = 0; reg < 4; ++reg) {
                    int f = mt*16 + quad*4 + reg;
                    WTl[r*WTS + f*8 + u] = valid ? f2bf(C[mt][reg]) : (ushort_t)0;
                }
            }
        }
    }

    {   // packed store: 8 m's of this block = (ki, q) fixed, j = 0..7
        int ki = nl0 >> 5;
        int q  = (nl0 >> 3) & 3;
        int ft = lane >> 4, rr = lane & 15;
        size_t tbase = (size_t)(b*NBT + wid*TT) * WTILE
                     + (size_t)(ki*4 + ft)*512 + q*128 + rr*8;
        #pragma unroll
        for (int t = 0; t < TT; ++t) {
            short8 v = *(const short8*)&WTl[t*WTS + lane*8];
            *(short8*)(WhT + tbase + (size_t)t*WTILE) = v;
        }
    }
}

// ---------------------------------------------------------------------------
// K42: FUSED layer-1 head-mix (k4 body) + layer-2 Wh/e (k2 body).
// ---------------------------------------------------------------------------
__global__ __launch_bounds__(256) void k42_fused(const ushort_t* __restrict__ hprB,
                                                 const ushort_t* __restrict__ WgB,
                                                 const float* __restrict__ bg,
                                                 const ushort_t* __restrict__ xB,
                                                 ushort_t* __restrict__ h1B,
                                                 const ushort_t* __restrict__ WtB,
                                                 const float* __restrict__ p1,
                                                 const float* __restrict__ p2,
                                                 ushort_t* __restrict__ WhT,
                                                 float* __restrict__ e1,
                                                 float* __restrict__ e2) {
    __shared__ ushort_t WTu[4*TT*WTS];    // 49920 B
    __shared__ ushort_t Bs[8][TT*KST];    // 13056 B  (total 62976 B)
    int tid  = threadIdx.x;
    int wid  = tid >> 6;
    int lane = tid & 63;
    int quad = lane >> 4;
    int r    = lane & 15;
    int b    = blockIdx.x / 63;
    int nl0  = (blockIdx.x % 63) * 8;

    // stage xB -> Bs (coalesced short8; clamp OOB tail)
    for (int i = tid; i < 8*TT*8; i += 256) {
        int u = i / 96, rem = i % 96;
        int t = rem >> 3, c8 = rem & 7;
        int node = b*NN + nl0 + u;
        if (node > NNODE-1) node = NNODE-1;
        *(short8*)&Bs[u][t*KST + c8*8] =
            *(const short8*)(xB + (size_t)node*CT + t*64 + c8*8);
    }
    __syncthreads();

    // ---- phase A (k4 body): nodes u = wid, wid+4 ----
    {
        short8 Ag[4][8];
        #pragma unroll
        for (int ot = 0; ot < 4; ++ot)
            #pragma unroll
            for (int kc = 0; kc < 8; ++kc)
                Ag[ot][kc] = *(const short8*)(WgB + (size_t)(ot*16 + r)*HF + kc*32 + quad*8);
        float4 bgv[4];
        #pragma unroll
        for (int ot = 0; ot < 4; ++ot)
            bgv[ot] = *(const float4*)(bg + ot*16 + quad*4);

        int tcl = r < TT ? r : TT-1;

        for (int p = 0; p < 2; ++p) {
            int u  = wid + p*4;
            int nl = nl0 + u;
            int node = b*NN + nl;
            int nodec = node > NNODE-1 ? NNODE-1 : node;
            const ushort_t* P = hprB + (size_t)nodec * (NBT*FF);

            floatx4 C[4];
            #pragma unroll
            for (int ot = 0; ot < 4; ++ot) C[ot] = (floatx4){0.f,0.f,0.f,0.f};
            #pragma unroll
            for (int kc = 0; kc < 8; ++kc) {
                int k = kc*32 + quad*8;
                int h = k >> 6, f0 = k & 63;
                short8 bfr = *(const short8*)(P + (h*TT + tcl)*FF + f0);
                #pragma unroll
                for (int ot = 0; ot < 4; ++ot)
                    C[ot] = __builtin_amdgcn_mfma_f32_16x16x32_bf16(Ag[ot][kc], bfr, C[ot], 0, 0, 0);
            }

            if (r < TT && nl < NN) {
                ushort_t* hp = h1B + (size_t)node*CT;
                #pragma unroll
                for (int ot = 0; ot < 4; ++ot) {
                    #pragma unroll
                    for (int rp = 0; rp < 4; rp += 2) {
                        int o = ot*16 + quad*4 + rp;      // even
                        uint_t xu = *(const uint_t*)&Bs[u][r*KST + o];
                        float x0 = bf2f((ushort_t)(xu & 0xffffu));
                        float x1 = bf2f((ushort_t)(xu >> 16));
                        float v0 = C[ot][rp]   + bgv[ot][rp];
                        float v1 = C[ot][rp+1] + bgv[ot][rp+1];
                        uint_t pv = pkbf(0.05f*x0 + 0.95f*v0,
                                         0.05f*x1 + 0.95f*v1);
                        *(uint_t*)&Bs[u][r*KST + o] = pv;   // h1 into LDS
                        *(uint_t*)&hp[r*64 + o]     = pv;   // h1B for k45
                    }
                }
            }
        }
    }
    __syncthreads();                      // Bs now holds h1 rows

    // ---- phase B (k2 body): e1/e2 + Wh MFMA + packed WhT store ----
    {
        int t2 = lane & 15, h2 = lane >> 4;
        if (t2 < TT) {
            for (int pass = 0; pass < 2; ++pass) {
                int u  = wid + pass*4;
                int nl = nl0 + u;
                if (nl < NN) {
                    const ushort_t* Bu = Bs[u];
                    float s1 = 0.f, s2 = 0.f;
                    for (int c = 0; c < CC; ++c) {
                        float v = bf2f(Bu[t2*KST + c]);
                        s1 += v * p1[h2*CC + c];
                        s2 += v * p2[h2*CC + c];
                    }
                    int idx = ((b*HH + h2)*TT + t2)*NN + nl;
                    e1[idx] = s1;
                    e2[idx] = s2;
                }
            }
        }
    }

    ushort_t* WTl = WTu + wid*(TT*WTS);

    short8 Afr[4][2];
    #pragma unroll
    for (int mt = 0; mt < 4; ++mt)
        #pragma unroll
        for (int kc = 0; kc < 2; ++kc)
            Afr[mt][kc] = *(const short8*)(WtB + wid*4096 +
                                           (mt*16 + r)*64 + kc*32 + quad*8);

    int rcl = r < TT ? r : TT-1;

    for (int u = 0; u < 8; ++u) {
        bool valid = (nl0 + u) < NN;
        floatx4 C[4];
        #pragma unroll
        for (int mt = 0; mt < 4; ++mt) C[mt] = (floatx4){0.f,0.f,0.f,0.f};
        #pragma unroll
        for (int kc = 0; kc < 2; ++kc) {
            short8 bfr = *(const short8*)&Bs[u][rcl*KST + kc*32 + quad*8];
            #pragma unroll
            for (int mt = 0; mt < 4; ++mt)
                C[mt] = __builtin_amdgcn_mfma_f32_16x16x32_bf16(Afr[mt][kc], bfr, C[mt], 0, 0, 0);
        }
        if (r < TT) {
            #pragma unroll
            for (int mt = 0; mt < 4; ++mt) {
                #pragma unroll
                for (int reg = 0; reg < 4; ++reg) {
                    int f = mt*16 + quad*4 + reg;
                    WTl[r*WTS + f*8 + u] = valid ? f2bf(C[mt][reg]) : (ushort_t)0;
                }
            }
        }
    }

    {   // packed store (same as k2)
        int ki = nl0 >> 5;
        int q  = (nl0 >> 3) & 3;
        int ft = lane >> 4, rr = lane & 15;
        size_t tbase = (size_t)(b*NBT + wid*TT) * WTILE
                     + (size_t)(ki*4 + ft)*512 + q*128 + rr*8;
        #pragma unroll
        for (int t = 0; t < TT; ++t) {
            short8 v = *(const short8*)&WTl[t*WTS + lane*8];
            *(short8*)(WhT + tbase + (size_t)t*WTILE) = v;
        }
    }
}

// ---------------------------------------------------------------------------
// K3: attention PV via MFMA — R4 schedule (half-split, 3 blocks/CU, ki+1
// prefetch, setprio) + packed-fp32 VALU for the softmax-numerator build:
// v_pk_add_f32 / v_pk_mul_f32 collapse the per-column-pair add/mul pairs
// into single VOP3P instructions.  Bit-identical IEEE fp32 per half ->
// numerics identical to R4.  (No v_pk_max_f32 on CDNA; max/exp stay scalar.)
// ---------------------------------------------------------------------------
__global__ __launch_bounds__(256, 3) void k3_attn(const ushort_t* __restrict__ WhT,
                                                  const float* __restrict__ e1,
                                                  const float* __restrict__ e2,
                                                  const uint_t* __restrict__ maskbits,
                                                  ushort_t* __restrict__ hprB) {
    __shared__ float  e2s[512];           // 2 KB
    __shared__ uint_t mks[256*17];        // 17408 B
    int tid  = threadIdx.x;
    int wid  = tid >> 6;
    int lane = tid & 63;
    int bht  = blockIdx.x >> 1;
    int half = blockIdx.x & 1;
    int b    = bht / NBT;
    int ht   = bht % NBT;

    const float* e1p = e1 + (size_t)bht * NN;
    const float* e2p = e2 + (size_t)bht * NN;
    const ushort_t* WTp = WhT + (size_t)bht * WTILE;
    const float L2E = 1.4426950408889634f;

    {
        int i = tid;
        e2s[i] = (i < NN) ? e2p[i] * L2E : 0.f;
        i = tid + 256;
        e2s[i] = (i < NN) ? e2p[i] * L2E : 0.f;
    }
    for (int i = tid; i < 256*16; i += 256) {
        int rl = i >> 4, dw = i & 15;
        mks[rl*17 + dw] = maskbits[(half*256 + rl)*16 + dw];
    }
    __syncthreads();

    int quad = lane >> 4;                 // 0..3
    int r    = lane & 15;                 // A-row / C-col

    const short8 ONES = {0x3F80,0x3F80,0x3F80,0x3F80,
                         0x3F80,0x3F80,0x3F80,0x3F80}; // bf16 1.0 x8

    float e1v[4];
    #pragma unroll
    for (int u = 0; u < 4; ++u) {
        int nrow = half*256 + (wid*4 + u)*16 + r;
        e1v[u] = ((nrow < NN) ? e1p[nrow] : 0.f) * L2E;
    }
    int rl0 = wid*64 + r;

    const ushort_t* WTl8 = WTp + lane*8;  // lane's fragment base

    floatx4 C[4][4];
    floatx4 Cs[4];
    #pragma unroll
    for (int u = 0; u < 4; ++u) {
        Cs[u] = (floatx4){0.f,0.f,0.f,0.f};
        #pragma unroll
        for (int ft = 0; ft < 4; ++ft) C[u][ft] = (floatx4){0.f,0.f,0.f,0.f};
    }

    // hoisted packed operands
    const float2v FIFTH = {0.2f, 0.2f};
    float2v e1pp[4];
    #pragma unroll
    for (int u = 0; u < 4; ++u) { e1pp[u].x = e1v[u]; e1pp[u].y = e1v[u]; }

    // prefetch ki=0 fragments
    short8 nbf[4];
    #pragma unroll
    for (int ft = 0; ft < 4; ++ft)
        nbf[ft] = *(const short8*)(WTl8 + (size_t)ft*512);

    #pragma unroll
    for (int ki = 0; ki < 16; ++ki) {
        int kb = ki*32 + quad*8;

        short8 b0 = nbf[0], b1 = nbf[1], b2 = nbf[2], b3 = nbf[3];
        if (ki < 15) {                    // compile-time after unroll
            #pragma unroll
            for (int ft = 0; ft < 4; ++ft)
                nbf[ft] = *(const short8*)(WTl8 + (size_t)((ki+1)*4 + ft)*512);
        }

        float4 ea = *(const float4*)&e2s[kb];
        float4 eb = *(const float4*)&e2s[kb + 4];
        float2v evp[4];
        evp[0].x = ea.x; evp[0].y = ea.y;
        evp[1].x = ea.z; evp[1].y = ea.w;
        evp[2].x = eb.x; evp[2].y = eb.y;
        evp[3].x = eb.z; evp[3].y = eb.w;

        #pragma unroll
        for (int u = 0; u < 4; ++u) {
            uint_t md    = mks[(rl0 + u*16)*17 + ki];
            uint_t mbits = md >> (quad*8);
            union { uint_t w[4]; short8 s; } av;
            #pragma unroll
            for (int p = 0; p < 4; ++p) {
                float2v s01, t01;
                asm("v_pk_add_f32 %0, %1, %2" : "=v"(s01) : "v"(e1pp[u]), "v"(evp[p]));
                asm("v_pk_mul_f32 %0, %1, %2" : "=v"(t01) : "v"(FIFTH), "v"(s01));
                float g0 = fmaxf(s01.x, t01.x);
                float g1 = fmaxf(s01.y, t01.y);
                float x0 = __builtin_amdgcn_exp2f(g0);
                float x1 = __builtin_amdgcn_exp2f(g1);
                x0 = (mbits & (1u << (2*p)))     ? x0 : 0.f;
                x1 = (mbits & (1u << (2*p + 1))) ? x1 : 0.f;
                av.w[p] = pkbf(x0, x1);
            }
            __builtin_amdgcn_s_setprio(1);
            C[u][0] = __builtin_amdgcn_mfma_f32_16x16x32_bf16(av.s, b0, C[u][0], 0, 0, 0);
            C[u][1] = __builtin_amdgcn_mfma_f32_16x16x32_bf16(av.s, b1, C[u][1], 0, 0, 0);
            C[u][2] = __builtin_amdgcn_mfma_f32_16x16x32_bf16(av.s, b2, C[u][2], 0, 0, 0);
            C[u][3] = __builtin_amdgcn_mfma_f32_16x16x32_bf16(av.s, b3, C[u][3], 0, 0, 0);
            Cs[u]   = __builtin_amdgcn_mfma_f32_16x16x32_bf16(av.s, ONES, Cs[u], 0, 0, 0);
            __builtin_amdgcn_s_setprio(0);
        }
    }

    #pragma unroll
    for (int u = 0; u < 4; ++u) {
        int n0 = half*256 + (wid*4 + u)*16;
        #pragma unroll
        for (int reg = 0; reg < 4; ++reg) {
            int n = n0 + quad*4 + reg;
            if (n < NN) {
                float inv = 1.0f / Cs[u][reg];
                size_t base = ((size_t)(b*NN + n)*NBT + ht)*FF;
                #pragma unroll
                for (int ft = 0; ft < 4; ++ft) {
                    float v = C[u][ft][reg] * inv;
                    v = v > 0.f ? v : __expf(v) - 1.f;
                    hprB[base + ft*16 + r] = f2bf(v);
                }
            }
        }
    }
}

// ---------------------------------------------------------------------------
// K45: fused layer-2 head-mix + final mix, BOTH via MFMA.  1 node/wave.
// (frozen from R19)
// ---------------------------------------------------------------------------
__global__ __launch_bounds__(256) void k45_fused(const ushort_t* __restrict__ hprB,
                                                 const ushort_t* __restrict__ WgB,
                                                 const float* __restrict__ bg,
                                                 const ushort_t* __restrict__ xB,
                                                 const ushort_t* __restrict__ h1B,
                                                 const ushort_t* __restrict__ WmB,
                                                 const float* __restrict__ bm,
                                                 float* __restrict__ out) {
    __shared__ ushort_t Bs[4][TT*BSR];    // 19200 B
    __shared__ float    So[4][CT];        // 12288 B
    int wid  = threadIdx.x >> 6;
    int lane = threadIdx.x & 63;
    int quad = lane >> 4;
    int r    = lane & 15;

    int node = blockIdx.x*4 + wid;
    ushort_t* Bw = Bs[wid];

    {   // stage xB, h1B -> sections 0,1 (short8 copies)
        const ushort_t* xp = xB  + (size_t)node*CT;
        const ushort_t* hp = h1B + (size_t)node*CT;
        for (int task = lane; task < 96; task += 64) {
            int t = task >> 3, c8 = task & 7;
            *(short8*)&Bw[t*BSR + c8*8]      = *(const short8*)(xp + t*64 + c8*8);
            *(short8*)&Bw[t*BSR + 64 + c8*8] = *(const short8*)(hp + t*64 + c8*8);
        }
    }

    // ---- phase 1 (k4 body): h2 via MFMA -> Bs section 2 ----
    {
        short8 Afr[4][8];
        #pragma unroll
        for (int ot = 0; ot < 4; ++ot)
            #pragma unroll
            for (int kc = 0; kc < 8; ++kc)
                Afr[ot][kc] = *(const short8*)(WgB + (size_t)(ot*16 + r)*HF + kc*32 + quad*8);
        float4 bgv[4];
        #pragma unroll
        for (int ot = 0; ot < 4; ++ot)
            bgv[ot] = *(const float4*)(bg + ot*16 + quad*4);

        int tcl = r < TT ? r : TT-1;
        const ushort_t* P = hprB + (size_t)node * (NBT*FF);

        floatx4 C[4];
        #pragma unroll
        for (int ot = 0; ot < 4; ++ot) C[ot] = (floatx4){0.f,0.f,0.f,0.f};
        #pragma unroll
        for (int kc = 0; kc < 8; ++kc) {
            int k = kc*32 + quad*8;
            int h = k >> 6, f0 = k & 63;
            short8 bfr = *(const short8*)(P + (h*TT + tcl)*FF + f0);
            #pragma unroll
            for (int ot = 0; ot < 4; ++ot)
                C[ot] = __builtin_amdgcn_mfma_f32_16x16x32_bf16(Afr[ot][kc], bfr, C[ot], 0, 0, 0);
        }

        if (r < TT) {
            #pragma unroll
            for (int ot = 0; ot < 4; ++ot) {
                #pragma unroll
                for (int rp = 0; rp < 4; rp += 2) {
                    int o = ot*16 + quad*4 + rp;
                    float v0 = C[ot][rp]   + bgv[ot][rp];
                    float v1 = C[ot][rp+1] + bgv[ot][rp+1];
                    float x0 = bf2f(Bw[r*BSR + o]);
                    float x1 = bf2f(Bw[r*BSR + o + 1]);
                    float h20 = 0.05f*x0 + 0.95f*v0;
                    float h21 = 0.05f*x1 + 0.95f*v1;
                    *(uint_t*)&Bw[r*BSR + 128 + o] = pkbf(h20, h21);
                }
            }
        }
    }

    // ---- phase 2 (k5 body): out = bm + WmB @ [x|h1|h2] via MFMA ----
    {
        short8 Am[4][6];
        #pragma unroll
        for (int ot = 0; ot < 4; ++ot)
            #pragma unroll
            for (int kc = 0; kc < 6; ++kc)
                Am[ot][kc] = *(const short8*)(WmB + (size_t)(ot*16 + r)*(3*CC) + kc*32 + quad*8);

        int trd = r < TT ? r : TT-1;      // clamp (rows 12..15 unused)
        floatx4 C2[4];
        #pragma unroll
        for (int ot = 0; ot < 4; ++ot) C2[ot] = (floatx4){0.f,0.f,0.f,0.f};
        #pragma unroll
        for (int kc = 0; kc < 6; ++kc) {
            short8 bfr = *(const short8*)&Bw[trd*BSR + kc*32 + quad*8];
            #pragma unroll
            for (int ot = 0; ot < 4; ++ot)
                C2[ot] = __builtin_amdgcn_mfma_f32_16x16x32_bf16(Am[ot][kc], bfr, C2[ot], 0, 0, 0);
        }

        if (r < TT) {
            #pragma unroll
            for (int ot = 0; ot < 4; ++ot) {
                float4 bmv = *(const float4*)(bm + ot*16 + quad*4);
                #pragma unroll
                for (int reg = 0; reg < 4; ++reg) {
                    int o = ot*16 + quad*4 + reg;
                    So[wid][o*TT + r] = C2[ot][reg] + bmv[reg];
                }
            }
        }
    }
    __syncthreads();

    {
        int o = threadIdx.x >> 2;
        int q = threadIdx.x & 3;
        int nodeq = blockIdx.x*4 + q;
        int bq = nodeq / NN, nq = nodeq % NN;
        float* op = out + ((size_t)(bq*CC + o)*NN + nq)*TT;
        const float* Sp = So[q] + o*TT;
        *(float4*)&op[0] = *(const float4*)&Sp[0];
        *(float4*)&op[4] = *(const float4*)&Sp[4];
        *(float4*)&op[8] = *(const float4*)&Sp[8];
    }
}

// ---------------------------------------------------------------------------
extern "C" void kernel_launch(void* const* d_in, const int* in_sizes, int n_in,
                              void* d_out, int out_size, void* d_ws, size_t ws_size,
                              hipStream_t stream) {
    const float* x   = (const float*)d_in[0];
    const float* adj = (const float*)d_in[1];
    const float* W   = (const float*)d_in[2];
    const float* a1  = (const float*)d_in[3];
    const float* a2  = (const float*)d_in[4];
    const float* Wg  = (const float*)d_in[5];
    const float* bg  = (const float*)d_in[6];
    const float* Wm  = (const float*)d_in[7];
    const float* bm  = (const float*)d_in[8];
    float* out = (float*)d_out;

    char* ws = (char*)d_ws;
    size_t off = 0;
    auto alloc = [&](size_t bytes) -> void* {
        void* p = ws + off;
        off += (bytes + 255) & ~(size_t)255;
        return p;
    };

    uint_t* maskbits = (uint_t*)alloc((size_t)512 * 16 * 4);                // 32 KB
    float* p1   = (float*)alloc(HH*CC * sizeof(float));
    float* p2   = (float*)alloc(HH*CC * sizeof(float));
    ushort_t* WmB = (ushort_t*)alloc((size_t)CC*3*CC * 2);                  // 24.6 KB
    ushort_t* WgB = (ushort_t*)alloc((size_t)FF*HF * 2);
    ushort_t* WtB = (ushort_t*)alloc((size_t)HH*CC*FF * 2);                 // 32 KB
    ushort_t* xB  = (ushort_t*)alloc((size_t)NNODE * CT * 2);               // 6.15 MB
    ushort_t* WhT  = (ushort_t*)alloc((size_t)NBHT * WTILE * 2);            // 25.2 MB
    ushort_t* hprB = (ushort_t*)alloc((size_t)NNODE * NBT * FF * 2);        // 24.6 MB
    float* e1   = (float*)alloc((size_t)NROWS * sizeof(float));
    float* e2   = (float*)alloc((size_t)NROWS * sizeof(float));
    ushort_t* h1B = (ushort_t*)alloc((size_t)NNODE * CT * 2);               // 6.15 MB
    (void)ws_size;

    k016_setup<<<561, 256, 0, stream>>>(adj, W, a1, a2, Wm, Wg, x,
                                        maskbits, p1, p2, WmB, WgB, WtB, xB, WhT);

    // layer 1
    k2_wh_e <<<8*63,    256, 0, stream>>>(xB, WtB, p1, p2, WhT, e1, e2);
    k3_attn <<<NBHT*2,  256, 0, stream>>>(WhT, e1, e2, maskbits, hprB);

    // fused: layer-1 head-mix + layer-2 Wh/e  (k4 + k2 in one launch)
    k42_fused<<<8*63,   256, 0, stream>>>(hprB, WgB, bg, xB, h1B,
                                          WtB, p1, p2, WhT, e1, e2);

    // layer 2 attention
    k3_attn <<<NBHT*2,  256, 0, stream>>>(WhT, e1, e2, maskbits, hprB);

    // fused layer-2 mix + final
    k45_fused<<<NNODE/4, 256, 0, stream>>>(hprB, WgB, bg, xB, h1B, WmB, bm, out);
}

// Round 6
// 246.057 us; speedup vs baseline: 1.0816x; 1.0816x over previous
//
#include <hip/hip_runtime.h>
#include <hip/hip_bf16.h>
#include <math.h>

#define BB 8
#define CC 64
#define NN 500
#define TT 12
#define HH 4
#define FF 64
#define CT (CC*TT)      // 768
#define HF (HH*FF)      // 256
#define NBT (HH*TT)     // 48
#define NBHT (BB*NBT)   // 384
#define NROWS (BB*HH*TT*NN)  // 192000
#define NNODE (BB*NN)   // 4000
#define BSR 200         // k45 LDS row stride (ushorts)
#define KST 68          // k2 LDS B row stride (ushorts)
#define WTS 520         // k2 WT-lds t-row stride (ushorts)
#define WTILE 32768     // packed WhT tile size per bht (ushorts) = 64KB

typedef unsigned short ushort_t;
typedef unsigned int uint_t;
typedef __attribute__((ext_vector_type(8))) short short8;
typedef __attribute__((ext_vector_type(4))) float floatx4;

static __device__ __forceinline__ ushort_t f2bf(float v) {
    __hip_bfloat16 h = __float2bfloat16(v);
    ushort_t u;
    __builtin_memcpy(&u, &h, 2);
    return u;
}

static __device__ __forceinline__ float bf2f(ushort_t u) {
    return __uint_as_float(((uint_t)u) << 16);
}

// pack two f32 -> packed bf16 (lo = a, hi = b), RNE (hw v_cvt_pk on gfx950)
static __device__ __forceinline__ uint_t pkbf(float a, float b) {
    __hip_bfloat162 h = __float22bfloat162_rn(make_float2(a, b));
    uint_t u;
    __builtin_memcpy(&u, &h, 4);
    return u;
}

// Packed WhT layout, per bht tile of WTILE ushorts:
//   element (f = ft*16 + r, m = ki*32 + q*8 + j)
//   -> offset (ki*4 + ft)*512 + q*128 + r*8 + j
// so k3's B-fragment load for (ki, ft) is lane*8 contiguous (1KB/instr).
//
// pAB layout: per head h, a 16x64 bf16 A-tile (rows: 0=p1_hi, 1=p1_lo,
// 2=p2_hi, 3=p2_lo, 4..15=0).  e1 = h·p1 is computed by MFMA alongside Wh:
// e1 = C5[0]+C5[1], e2 = C5[2]+C5[3] (hi+lo residual split keeps fp32-level
// accuracy of the p vectors).

// ---------------------------------------------------------------------------
// K016: merged setup + x-transpose(->bf16) + packed-WhT tail zero.
// Branch map: [0,32) maskbits | [32,225) weights+pAB | [225,481) x-transpose
//             | [481,577) WhT tail zero.
// ---------------------------------------------------------------------------
__global__ __launch_bounds__(256) void k016_setup(const float* __restrict__ adj,
                                                  const float* __restrict__ W,
                                                  const float* __restrict__ a1,
                                                  const float* __restrict__ a2,
                                                  const float* __restrict__ Wm,
                                                  const float* __restrict__ Wg,
                                                  const float* __restrict__ x,
                                                  uint_t* __restrict__ maskbits,
                                                  ushort_t* __restrict__ pAB,
                                                  ushort_t* __restrict__ WmB,
                                                  ushort_t* __restrict__ WgB,
                                                  ushort_t* __restrict__ WtB,
                                                  ushort_t* __restrict__ xB,
                                                  ushort_t* __restrict__ WhT) {
    __shared__ float tile[16*776];   // used by the x-transpose path only
    int blk = blockIdx.x;
    if (blk < 32) {
        int idx = blk * 256 + threadIdx.x;   // < 512*16
        int n = idx >> 4, j = idx & 15;      // dword j covers m = j*32..+31
        uint_t v = 0;
        if (n < NN) {
            int m0 = j * 32;
            for (int i = 0; i < 32; ++i) {
                int m = m0 + i;
                bool p = (m < NN) && (adj[n*NN + m] > 0.f || m == n);
                v |= (p ? 1u : 0u) << i;
            }
        }
        maskbits[idx] = v;
        return;
    }
    if (blk < 225) {
        int idx = (blk - 32) * 256 + threadIdx.x;
        if (idx < HH*16*CC) {                 // pAB A-tiles (4096)
            int h   = idx >> 10;
            int rem = idx & 1023;
            int row = rem >> 6, c = rem & 63;
            ushort_t val = 0;
            if (row < 4) {
                const float* av = (row < 2) ? a1 : a2;
                float s = 0.f;
                for (int f = 0; f < FF; ++f)
                    s += W[(h*CC + c)*FF + f] * av[h*FF + f];
                if ((row & 1) == 0) val = f2bf(s);
                else                val = f2bf(s - bf2f(f2bf(s)));  // residual
            }
            pAB[idx] = val;
        }
        int j = idx - HH*16*CC;
        if (j >= 0 && j < CC*3*CC) {          // WmB = bf16(Wm), [o][192]
            WmB[j] = f2bf(Wm[j]);
        }
        int j2 = idx - (HH*16*CC + CC*3*CC);
        if (j2 >= 0 && j2 < FF*HF) {
            WgB[j2] = f2bf(Wg[j2]);
        }
        int j3 = idx - (HH*16*CC + CC*3*CC + FF*HF);
        if (j3 >= 0 && j3 < HH*CC*FF) {       // WtB[h][f][c] = W[h][c][f]
            int h = j3 >> 12, rem = j3 & 4095;
            int f = rem >> 6, c = rem & 63;
            WtB[j3] = f2bf(W[h*4096 + c*64 + f]);
        }
        return;
    }
    if (blk >= 481) {                         // packed WhT tail zero: m in [500,512)
        int task = (blk - 481) * 256 + threadIdx.x;   // < 24576 = 384*64
        int tilei = task >> 6;       // 0..383 (bht)
        int ft    = (task >> 4) & 3;
        int r     = task & 15;
        ushort_t* base = WhT + (size_t)tilei*WTILE + (size_t)(15*4 + ft)*512;
        // m = 500..503: ki=15, q=2, j=4..7
        *(uint_t*)(base + 2*128 + r*8 + 4) = 0;
        *(uint_t*)(base + 2*128 + r*8 + 6) = 0;
        // m = 504..511: ki=15, q=3, j=0..7
        *(short8*)(base + 3*128 + r*8) = (short8){0,0,0,0,0,0,0,0};
        return;
    }
    // x-transpose: blocks 225..480 -> xblk 0..255; out bf16 [t][64c]
    int xblk = blk - 225;
    int b  = xblk >> 5;
    int n0 = (xblk & 31) * 16;
    for (int idx = threadIdx.x; idx < CC*16*TT; idx += 256) {
        int c   = idx / (16*TT);
        int rem = idx % (16*TT);
        int nl  = rem / TT;
        int t   = rem % TT;
        int n   = n0 + nl;
        if (n < NN)
            tile[nl*776 + c*TT + t] = x[((b*CC + c)*NN + n)*TT + t];
    }
    __syncthreads();
    for (int idx = threadIdx.x; idx < 16*384; idx += 256) {
        int nl = idx / 384, j = idx % 384;    // j = t*32 + c2
        int t = j >> 5, c2 = j & 31;
        int n = n0 + nl;
        if (n < NN) {
            float v0 = tile[nl*776 + (2*c2)*TT + t];
            float v1 = tile[nl*776 + (2*c2 + 1)*TT + t];
            *(uint_t*)&xB[(size_t)(b*NN + n)*CT + t*64 + 2*c2] = pkbf(v0, v1);
        }
    }
}

// ---------------------------------------------------------------------------
// K2: Wh via MFMA, writing packed WhT directly (layer 1; input xB).
// e1/e2 now computed via MFMA (pAB A-tile, C5 accumulator) in the same
// u-loop — replaces the 64-iteration serial dot-product block.
// ---------------------------------------------------------------------------
__global__ __launch_bounds__(256) void k2_wh_e(const ushort_t* __restrict__ hinB,
                                               const ushort_t* __restrict__ WtB,
                                               const ushort_t* __restrict__ pAB,
                                               ushort_t* __restrict__ WhT,
                                               float* __restrict__ e1,
                                               float* __restrict__ e2) {
    __shared__ ushort_t WTu[4*TT*WTS];    // 49920 B (per-wave transpose bufs)
    __shared__ ushort_t Bs[8][TT*KST];    // 13056 B
    int tid  = threadIdx.x;
    int wid  = tid >> 6;                  // wave = head h
    int lane = tid & 63;
    int quad = lane >> 4;
    int r    = lane & 15;
    int b    = blockIdx.x / 63;
    int nl0  = (blockIdx.x % 63) * 8;     // local m base (0..496)

    for (int i = tid; i < 8*TT*8; i += 256) {   // 768 short8 tasks
        int u = i / 96, rem = i % 96;
        int t = rem >> 3, c8 = rem & 7;
        int node = b*NN + nl0 + u;
        if (node > NNODE-1) node = NNODE-1;
        short8 v = *(const short8*)(hinB + (size_t)node*CT + t*64 + c8*8);
        *(short8*)&Bs[u][t*KST + c8*8] = v;
    }
    __syncthreads();

    ushort_t* WTl = WTu + wid*(TT*WTS);   // [12][520], wave-private

    short8 Afr[4][2];
    #pragma unroll
    for (int mt = 0; mt < 4; ++mt)
        #pragma unroll
        for (int kc = 0; kc < 2; ++kc)
            Afr[mt][kc] = *(const short8*)(WtB + wid*4096 +
                                           (mt*16 + r)*64 + kc*32 + quad*8);
    short8 pfr[2];
    #pragma unroll
    for (int kc = 0; kc < 2; ++kc)
        pfr[kc] = *(const short8*)(pAB + wid*1024 + r*64 + kc*32 + quad*8);

    int rcl = r < TT ? r : TT-1;

    for (int u = 0; u < 8; ++u) {
        bool valid = (nl0 + u) < NN;
        floatx4 C[4];
        floatx4 C5 = (floatx4){0.f,0.f,0.f,0.f};
        #pragma unroll
        for (int mt = 0; mt < 4; ++mt) C[mt] = (floatx4){0.f,0.f,0.f,0.f};
        #pragma unroll
        for (int kc = 0; kc < 2; ++kc) {
            short8 bfr = *(const short8*)&Bs[u][rcl*KST + kc*32 + quad*8];
            #pragma unroll
            for (int mt = 0; mt < 4; ++mt)
                C[mt] = __builtin_amdgcn_mfma_f32_16x16x32_bf16(Afr[mt][kc], bfr, C[mt], 0, 0, 0);
            C5 = __builtin_amdgcn_mfma_f32_16x16x32_bf16(pfr[kc], bfr, C5, 0, 0, 0);
        }
        if (quad == 0 && r < TT && valid) {   // rows 0..3 of C5 = p-dots, col r = t
            int ebase = ((b*HH + wid)*TT + r)*NN + nl0 + u;
            e1[ebase] = C5[0] + C5[1];
            e2[ebase] = C5[2] + C5[3];
        }
        if (r < TT) {
            #pragma unroll
            for (int mt = 0; mt < 4; ++mt) {
                #pragma unroll
                for (int reg = 0; reg < 4; ++reg) {
                    int f = mt*16 + quad*4 + reg;
                    WTl[r*WTS + f*8 + u] = valid ? f2bf(C[mt][reg]) : (ushort_t)0;
                }
            }
        }
    }

    {   // packed store: 8 m's of this block = (ki, q) fixed, j = 0..7
        int ki = nl0 >> 5;
        int q  = (nl0 >> 3) & 3;
        int ft = lane >> 4, rr = lane & 15;
        size_t tbase = (size_t)(b*NBT + wid*TT) * WTILE
                     + (size_t)(ki*4 + ft)*512 + q*128 + rr*8;
        #pragma unroll
        for (int t = 0; t < TT; ++t) {
            short8 v = *(const short8*)&WTl[t*WTS + lane*8];
            *(short8*)(WhT + tbase + (size_t)t*WTILE) = v;
        }
    }
}

// ---------------------------------------------------------------------------
// K42: FUSED layer-1 head-mix (k4 body) + layer-2 Wh/e (k2 body).
// e1/e2 via MFMA (same C5 scheme as k2).
// ---------------------------------------------------------------------------
__global__ __launch_bounds__(256) void k42_fused(const ushort_t* __restrict__ hprB,
                                                 const ushort_t* __restrict__ WgB,
                                                 const float* __restrict__ bg,
                                                 const ushort_t* __restrict__ xB,
                                                 ushort_t* __restrict__ h1B,
                                                 const ushort_t* __restrict__ WtB,
                                                 const ushort_t* __restrict__ pAB,
                                                 ushort_t* __restrict__ WhT,
                                                 float* __restrict__ e1,
                                                 float* __restrict__ e2) {
    __shared__ ushort_t WTu[4*TT*WTS];    // 49920 B
    __shared__ ushort_t Bs[8][TT*KST];    // 13056 B  (total 62976 B)
    int tid  = threadIdx.x;
    int wid  = tid >> 6;
    int lane = tid & 63;
    int quad = lane >> 4;
    int r    = lane & 15;
    int b    = blockIdx.x / 63;
    int nl0  = (blockIdx.x % 63) * 8;

    // stage xB -> Bs (coalesced short8; clamp OOB tail)
    for (int i = tid; i < 8*TT*8; i += 256) {
        int u = i / 96, rem = i % 96;
        int t = rem >> 3, c8 = rem & 7;
        int node = b*NN + nl0 + u;
        if (node > NNODE-1) node = NNODE-1;
        *(short8*)&Bs[u][t*KST + c8*8] =
            *(const short8*)(xB + (size_t)node*CT + t*64 + c8*8);
    }
    __syncthreads();

    // ---- phase A (k4 body): nodes u = wid, wid+4 ----
    {
        short8 Ag[4][8];
        #pragma unroll
        for (int ot = 0; ot < 4; ++ot)
            #pragma unroll
            for (int kc = 0; kc < 8; ++kc)
                Ag[ot][kc] = *(const short8*)(WgB + (size_t)(ot*16 + r)*HF + kc*32 + quad*8);
        float4 bgv[4];
        #pragma unroll
        for (int ot = 0; ot < 4; ++ot)
            bgv[ot] = *(const float4*)(bg + ot*16 + quad*4);

        int tcl = r < TT ? r : TT-1;

        for (int p = 0; p < 2; ++p) {
            int u  = wid + p*4;
            int nl = nl0 + u;
            int node = b*NN + nl;
            int nodec = node > NNODE-1 ? NNODE-1 : node;
            const ushort_t* P = hprB + (size_t)nodec * (NBT*FF);

            floatx4 C[4];
            #pragma unroll
            for (int ot = 0; ot < 4; ++ot) C[ot] = (floatx4){0.f,0.f,0.f,0.f};
            #pragma unroll
            for (int kc = 0; kc < 8; ++kc) {
                int k = kc*32 + quad*8;
                int h = k >> 6, f0 = k & 63;
                short8 bfr = *(const short8*)(P + (h*TT + tcl)*FF + f0);
                #pragma unroll
                for (int ot = 0; ot < 4; ++ot)
                    C[ot] = __builtin_amdgcn_mfma_f32_16x16x32_bf16(Ag[ot][kc], bfr, C[ot], 0, 0, 0);
            }

            if (r < TT && nl < NN) {
                ushort_t* hp = h1B + (size_t)node*CT;
                #pragma unroll
                for (int ot = 0; ot < 4; ++ot) {
                    #pragma unroll
                    for (int rp = 0; rp < 4; rp += 2) {
                        int o = ot*16 + quad*4 + rp;      // even
                        uint_t xu = *(const uint_t*)&Bs[u][r*KST + o];
                        float x0 = bf2f((ushort_t)(xu & 0xffffu));
                        float x1 = bf2f((ushort_t)(xu >> 16));
                        float v0 = C[ot][rp]   + bgv[ot][rp];
                        float v1 = C[ot][rp+1] + bgv[ot][rp+1];
                        uint_t pv = pkbf(0.05f*x0 + 0.95f*v0,
                                         0.05f*x1 + 0.95f*v1);
                        *(uint_t*)&Bs[u][r*KST + o] = pv;   // h1 into LDS
                        *(uint_t*)&hp[r*64 + o]     = pv;   // h1B for k45
                    }
                }
            }
        }
    }
    __syncthreads();                      // Bs now holds h1 rows

    // ---- phase B (k2 body): Wh MFMA + e via C5 + packed WhT store ----
    ushort_t* WTl = WTu + wid*(TT*WTS);

    short8 Afr[4][2];
    #pragma unroll
    for (int mt = 0; mt < 4; ++mt)
        #pragma unroll
        for (int kc = 0; kc < 2; ++kc)
            Afr[mt][kc] = *(const short8*)(WtB + wid*4096 +
                                           (mt*16 + r)*64 + kc*32 + quad*8);
    short8 pfr[2];
    #pragma unroll
    for (int kc = 0; kc < 2; ++kc)
        pfr[kc] = *(const short8*)(pAB + wid*1024 + r*64 + kc*32 + quad*8);

    int rcl = r < TT ? r : TT-1;

    for (int u = 0; u < 8; ++u) {
        bool valid = (nl0 + u) < NN;
        floatx4 C[4];
        floatx4 C5 = (floatx4){0.f,0.f,0.f,0.f};
        #pragma unroll
        for (int mt = 0; mt < 4; ++mt) C[mt] = (floatx4){0.f,0.f,0.f,0.f};
        #pragma unroll
        for (int kc = 0; kc < 2; ++kc) {
            short8 bfr = *(const short8*)&Bs[u][rcl*KST + kc*32 + quad*8];
            #pragma unroll
            for (int mt = 0; mt < 4; ++mt)
                C[mt] = __builtin_amdgcn_mfma_f32_16x16x32_bf16(Afr[mt][kc], bfr, C[mt], 0, 0, 0);
            C5 = __builtin_amdgcn_mfma_f32_16x16x32_bf16(pfr[kc], bfr, C5, 0, 0, 0);
        }
        if (quad == 0 && r < TT && valid) {
            int ebase = ((b*HH + wid)*TT + r)*NN + nl0 + u;
            e1[ebase] = C5[0] + C5[1];
            e2[ebase] = C5[2] + C5[3];
        }
        if (r < TT) {
            #pragma unroll
            for (int mt = 0; mt < 4; ++mt) {
                #pragma unroll
                for (int reg = 0; reg < 4; ++reg) {
                    int f = mt*16 + quad*4 + reg;
                    WTl[r*WTS + f*8 + u] = valid ? f2bf(C[mt][reg]) : (ushort_t)0;
                }
            }
        }
    }

    {   // packed store (same as k2)
        int ki = nl0 >> 5;
        int q  = (nl0 >> 3) & 3;
        int ft = lane >> 4, rr = lane & 15;
        size_t tbase = (size_t)(b*NBT + wid*TT) * WTILE
                     + (size_t)(ki*4 + ft)*512 + q*128 + rr*8;
        #pragma unroll
        for (int t = 0; t < TT; ++t) {
            short8 v = *(const short8*)&WTl[t*WTS + lane*8];
            *(short8*)(WhT + tbase + (size_t)t*WTILE) = v;
        }
    }
}

// ---------------------------------------------------------------------------
// K3: attention PV via MFMA — R4-exact (proven 46.5us): half-split,
// 3 blocks/CU, ki+1 B-fragment prefetch, setprio around MFMA cluster.
// (R5's pk-asm variant regressed: asm pairing constraints defeat the
// compiler scheduler.  Scalar VALU restored.)
// ---------------------------------------------------------------------------
__global__ __launch_bounds__(256, 3) void k3_attn(const ushort_t* __restrict__ WhT,
                                                  const float* __restrict__ e1,
                                                  const float* __restrict__ e2,
                                                  const uint_t* __restrict__ maskbits,
                                                  ushort_t* __restrict__ hprB) {
    __shared__ float  e2s[512];           // 2 KB
    __shared__ uint_t mks[256*17];        // 17408 B
    int tid  = threadIdx.x;
    int wid  = tid >> 6;
    int lane = tid & 63;
    int bht  = blockIdx.x >> 1;
    int half = blockIdx.x & 1;
    int b    = bht / NBT;
    int ht   = bht % NBT;

    const float* e1p = e1 + (size_t)bht * NN;
    const float* e2p = e2 + (size_t)bht * NN;
    const ushort_t* WTp = WhT + (size_t)bht * WTILE;
    const float L2E = 1.4426950408889634f;

    {
        int i = tid;
        e2s[i] = (i < NN) ? e2p[i] * L2E : 0.f;
        i = tid + 256;
        e2s[i] = (i < NN) ? e2p[i] * L2E : 0.f;
    }
    for (int i = tid; i < 256*16; i += 256) {
        int rl = i >> 4, dw = i & 15;
        mks[rl*17 + dw] = maskbits[(half*256 + rl)*16 + dw];
    }
    __syncthreads();

    int quad = lane >> 4;                 // 0..3
    int r    = lane & 15;                 // A-row / C-col

    const short8 ONES = {0x3F80,0x3F80,0x3F80,0x3F80,
                         0x3F80,0x3F80,0x3F80,0x3F80}; // bf16 1.0 x8

    float e1v[4];
    #pragma unroll
    for (int u = 0; u < 4; ++u) {
        int nrow = half*256 + (wid*4 + u)*16 + r;
        e1v[u] = ((nrow < NN) ? e1p[nrow] : 0.f) * L2E;
    }
    int rl0 = wid*64 + r;

    const ushort_t* WTl8 = WTp + lane*8;  // lane's fragment base

    floatx4 C[4][4];
    floatx4 Cs[4];
    #pragma unroll
    for (int u = 0; u < 4; ++u) {
        Cs[u] = (floatx4){0.f,0.f,0.f,0.f};
        #pragma unroll
        for (int ft = 0; ft < 4; ++ft) C[u][ft] = (floatx4){0.f,0.f,0.f,0.f};
    }

    // prefetch ki=0 fragments
    short8 nbf[4];
    #pragma unroll
    for (int ft = 0; ft < 4; ++ft)
        nbf[ft] = *(const short8*)(WTl8 + (size_t)ft*512);

    #pragma unroll
    for (int ki = 0; ki < 16; ++ki) {
        int kb = ki*32 + quad*8;

        short8 b0 = nbf[0], b1 = nbf[1], b2 = nbf[2], b3 = nbf[3];
        if (ki < 15) {                    // compile-time after unroll
            #pragma unroll
            for (int ft = 0; ft < 4; ++ft)
                nbf[ft] = *(const short8*)(WTl8 + (size_t)((ki+1)*4 + ft)*512);
        }

        float4 ea = *(const float4*)&e2s[kb];
        float4 eb = *(const float4*)&e2s[kb + 4];
        float ev[8] = {ea.x,ea.y,ea.z,ea.w, eb.x,eb.y,eb.z,eb.w};

        #pragma unroll
        for (int u = 0; u < 4; ++u) {
            uint_t md    = mks[(rl0 + u*16)*17 + ki];
            uint_t mbits = md >> (quad*8);
            union { uint_t w[4]; short8 s; } av;
            #pragma unroll
            for (int p = 0; p < 4; ++p) {
                float s0 = e1v[u] + ev[2*p];
                float s1 = e1v[u] + ev[2*p+1];
                float g0 = fmaxf(s0, 0.2f*s0);
                float g1 = fmaxf(s1, 0.2f*s1);
                float x0 = __builtin_amdgcn_exp2f(g0);
                float x1 = __builtin_amdgcn_exp2f(g1);
                x0 = (mbits & (1u << (2*p)))     ? x0 : 0.f;
                x1 = (mbits & (1u << (2*p + 1))) ? x1 : 0.f;
                av.w[p] = pkbf(x0, x1);
            }
            __builtin_amdgcn_s_setprio(1);
            C[u][0] = __builtin_amdgcn_mfma_f32_16x16x32_bf16(av.s, b0, C[u][0], 0, 0, 0);
            C[u][1] = __builtin_amdgcn_mfma_f32_16x16x32_bf16(av.s, b1, C[u][1], 0, 0, 0);
            C[u][2] = __builtin_amdgcn_mfma_f32_16x16x32_bf16(av.s, b2, C[u][2], 0, 0, 0);
            C[u][3] = __builtin_amdgcn_mfma_f32_16x16x32_bf16(av.s, b3, C[u][3], 0, 0, 0);
            Cs[u]   = __builtin_amdgcn_mfma_f32_16x16x32_bf16(av.s, ONES, Cs[u], 0, 0, 0);
            __builtin_amdgcn_s_setprio(0);
        }
    }

    #pragma unroll
    for (int u = 0; u < 4; ++u) {
        int n0 = half*256 + (wid*4 + u)*16;
        #pragma unroll
        for (int reg = 0; reg < 4; ++reg) {
            int n = n0 + quad*4 + reg;
            if (n < NN) {
                float inv = 1.0f / Cs[u][reg];
                size_t base = ((size_t)(b*NN + n)*NBT + ht)*FF;
                #pragma unroll
                for (int ft = 0; ft < 4; ++ft) {
                    float v = C[u][ft][reg] * inv;
                    v = v > 0.f ? v : __expf(v) - 1.f;
                    hprB[base + ft*16 + r] = f2bf(v);
                }
            }
        }
    }
}

// ---------------------------------------------------------------------------
// K45: fused layer-2 head-mix + final mix, BOTH via MFMA.  1 node/wave.
// (frozen from R19)
// ---------------------------------------------------------------------------
__global__ __launch_bounds__(256) void k45_fused(const ushort_t* __restrict__ hprB,
                                                 const ushort_t* __restrict__ WgB,
                                                 const float* __restrict__ bg,
                                                 const ushort_t* __restrict__ xB,
                                                 const ushort_t* __restrict__ h1B,
                                                 const ushort_t* __restrict__ WmB,
                                                 const float* __restrict__ bm,
                                                 float* __restrict__ out) {
    __shared__ ushort_t Bs[4][TT*BSR];    // 19200 B
    __shared__ float    So[4][CT];        // 12288 B
    int wid  = threadIdx.x >> 6;
    int lane = threadIdx.x & 63;
    int quad = lane >> 4;
    int r    = lane & 15;

    int node = blockIdx.x*4 + wid;
    ushort_t* Bw = Bs[wid];

    {   // stage xB, h1B -> sections 0,1 (short8 copies)
        const ushort_t* xp = xB  + (size_t)node*CT;
        const ushort_t* hp = h1B + (size_t)node*CT;
        for (int task = lane; task < 96; task += 64) {
            int t = task >> 3, c8 = task & 7;
            *(short8*)&Bw[t*BSR + c8*8]      = *(const short8*)(xp + t*64 + c8*8);
            *(short8*)&Bw[t*BSR + 64 + c8*8] = *(const short8*)(hp + t*64 + c8*8);
        }
    }

    // ---- phase 1 (k4 body): h2 via MFMA -> Bs section 2 ----
    {
        short8 Afr[4][8];
        #pragma unroll
        for (int ot = 0; ot < 4; ++ot)
            #pragma unroll
            for (int kc = 0; kc < 8; ++kc)
                Afr[ot][kc] = *(const short8*)(WgB + (size_t)(ot*16 + r)*HF + kc*32 + quad*8);
        float4 bgv[4];
        #pragma unroll
        for (int ot = 0; ot < 4; ++ot)
            bgv[ot] = *(const float4*)(bg + ot*16 + quad*4);

        int tcl = r < TT ? r : TT-1;
        const ushort_t* P = hprB + (size_t)node * (NBT*FF);

        floatx4 C[4];
        #pragma unroll
        for (int ot = 0; ot < 4; ++ot) C[ot] = (floatx4){0.f,0.f,0.f,0.f};
        #pragma unroll
        for (int kc = 0; kc < 8; ++kc) {
            int k = kc*32 + quad*8;
            int h = k >> 6, f0 = k & 63;
            short8 bfr = *(const short8*)(P + (h*TT + tcl)*FF + f0);
            #pragma unroll
            for (int ot = 0; ot < 4; ++ot)
                C[ot] = __builtin_amdgcn_mfma_f32_16x16x32_bf16(Afr[ot][kc], bfr, C[ot], 0, 0, 0);
        }

        if (r < TT) {
            #pragma unroll
            for (int ot = 0; ot < 4; ++ot) {
                #pragma unroll
                for (int rp = 0; rp < 4; rp += 2) {
                    int o = ot*16 + quad*4 + rp;
                    float v0 = C[ot][rp]   + bgv[ot][rp];
                    float v1 = C[ot][rp+1] + bgv[ot][rp+1];
                    float x0 = bf2f(Bw[r*BSR + o]);
                    float x1 = bf2f(Bw[r*BSR + o + 1]);
                    float h20 = 0.05f*x0 + 0.95f*v0;
                    float h21 = 0.05f*x1 + 0.95f*v1;
                    *(uint_t*)&Bw[r*BSR + 128 + o] = pkbf(h20, h21);
                }
            }
        }
    }

    // ---- phase 2 (k5 body): out = bm + WmB @ [x|h1|h2] via MFMA ----
    {
        short8 Am[4][6];
        #pragma unroll
        for (int ot = 0; ot < 4; ++ot)
            #pragma unroll
            for (int kc = 0; kc < 6; ++kc)
                Am[ot][kc] = *(const short8*)(WmB + (size_t)(ot*16 + r)*(3*CC) + kc*32 + quad*8);

        int trd = r < TT ? r : TT-1;      // clamp (rows 12..15 unused)
        floatx4 C2[4];
        #pragma unroll
        for (int ot = 0; ot < 4; ++ot) C2[ot] = (floatx4){0.f,0.f,0.f,0.f};
        #pragma unroll
        for (int kc = 0; kc < 6; ++kc) {
            short8 bfr = *(const short8*)&Bw[trd*BSR + kc*32 + quad*8];
            #pragma unroll
            for (int ot = 0; ot < 4; ++ot)
                C2[ot] = __builtin_amdgcn_mfma_f32_16x16x32_bf16(Am[ot][kc], bfr, C2[ot], 0, 0, 0);
        }

        if (r < TT) {
            #pragma unroll
            for (int ot = 0; ot < 4; ++ot) {
                float4 bmv = *(const float4*)(bm + ot*16 + quad*4);
                #pragma unroll
                for (int reg = 0; reg < 4; ++reg) {
                    int o = ot*16 + quad*4 + reg;
                    So[wid][o*TT + r] = C2[ot][reg] + bmv[reg];
                }
            }
        }
    }
    __syncthreads();

    {
        int o = threadIdx.x >> 2;
        int q = threadIdx.x & 3;
        int nodeq = blockIdx.x*4 + q;
        int bq = nodeq / NN, nq = nodeq % NN;
        float* op = out + ((size_t)(bq*CC + o)*NN + nq)*TT;
        const float* Sp = So[q] + o*TT;
        *(float4*)&op[0] = *(const float4*)&Sp[0];
        *(float4*)&op[4] = *(const float4*)&Sp[4];
        *(float4*)&op[8] = *(const float4*)&Sp[8];
    }
}

// ---------------------------------------------------------------------------
extern "C" void kernel_launch(void* const* d_in, const int* in_sizes, int n_in,
                              void* d_out, int out_size, void* d_ws, size_t ws_size,
                              hipStream_t stream) {
    const float* x   = (const float*)d_in[0];
    const float* adj = (const float*)d_in[1];
    const float* W   = (const float*)d_in[2];
    const float* a1  = (const float*)d_in[3];
    const float* a2  = (const float*)d_in[4];
    const float* Wg  = (const float*)d_in[5];
    const float* bg  = (const float*)d_in[6];
    const float* Wm  = (const float*)d_in[7];
    const float* bm  = (const float*)d_in[8];
    float* out = (float*)d_out;

    char* ws = (char*)d_ws;
    size_t off = 0;
    auto alloc = [&](size_t bytes) -> void* {
        void* p = ws + off;
        off += (bytes + 255) & ~(size_t)255;
        return p;
    };

    uint_t* maskbits = (uint_t*)alloc((size_t)512 * 16 * 4);                // 32 KB
    ushort_t* pAB = (ushort_t*)alloc((size_t)HH*16*CC * 2);                 // 8 KB
    ushort_t* WmB = (ushort_t*)alloc((size_t)CC*3*CC * 2);                  // 24.6 KB
    ushort_t* WgB = (ushort_t*)alloc((size_t)FF*HF * 2);
    ushort_t* WtB = (ushort_t*)alloc((size_t)HH*CC*FF * 2);                 // 32 KB
    ushort_t* xB  = (ushort_t*)alloc((size_t)NNODE * CT * 2);               // 6.15 MB
    ushort_t* WhT  = (ushort_t*)alloc((size_t)NBHT * WTILE * 2);            // 25.2 MB
    ushort_t* hprB = (ushort_t*)alloc((size_t)NNODE * NBT * FF * 2);        // 24.6 MB
    float* e1   = (float*)alloc((size_t)NROWS * sizeof(float));
    float* e2   = (float*)alloc((size_t)NROWS * sizeof(float));
    ushort_t* h1B = (ushort_t*)alloc((size_t)NNODE * CT * 2);               // 6.15 MB
    (void)ws_size;

    k016_setup<<<577, 256, 0, stream>>>(adj, W, a1, a2, Wm, Wg, x,
                                        maskbits, pAB, WmB, WgB, WtB, xB, WhT);

    // layer 1
    k2_wh_e <<<8*63,    256, 0, stream>>>(xB, WtB, pAB, WhT, e1, e2);
    k3_attn <<<NBHT*2,  256, 0, stream>>>(WhT, e1, e2, maskbits, hprB);

    // fused: layer-1 head-mix + layer-2 Wh/e  (k4 + k2 in one launch)
    k42_fused<<<8*63,   256, 0, stream>>>(hprB, WgB, bg, xB, h1B,
                                          WtB, pAB, WhT, e1, e2);

    // layer 2 attention
    k3_attn <<<NBHT*2,  256, 0, stream>>>(WhT, e1, e2, maskbits, hprB);

    // fused layer-2 mix + final
    k45_fused<<<NNODE/4, 256, 0, stream>>>(hprB, WgB, bg, xB, h1B, WmB, bm, out);
}